// Round 1
// baseline (158.473 us; speedup 1.0000x reference)
//
#include <hip/hip_runtime.h>
#include <hip/hip_bf16.h>
#include <math.h>

typedef __attribute__((ext_vector_type(8))) short s16x8;
typedef __attribute__((ext_vector_type(4))) float f32x4;
typedef __attribute__((ext_vector_type(2))) float f32x2;

__device__ __forceinline__ unsigned short f2bf(float f) {
    union { float f; unsigned int u; } v; v.f = f;
    unsigned int u = v.u + 0x7FFFu + ((v.u >> 16) & 1u);
    return (unsigned short)(u >> 16);
}
__device__ __forceinline__ unsigned pk2(float lo, float hi) {
    __hip_bfloat162 h = __float22bfloat162_rn(make_float2(lo, hi));
    union { __hip_bfloat162 h; unsigned u; } v; v.h = h;
    return v.u;
}
__device__ __forceinline__ float blo(unsigned u) {
    union { unsigned u; float f; } v; v.u = u << 16; return v.f;
}
__device__ __forceinline__ float bhi(unsigned u) {
    union { unsigned u; float f; } v; v.u = u & 0xffff0000u; return v.f;
}

// Blend 4 corner uint2s (4 bf16 channels each) into one packed uint2, store to LDS.
// float2 vector math so LLVM can emit v_pk_fma_f32.
__device__ __forceinline__ void blend_store2(uint2 uA, uint2 uB, uint2 uC, uint2 uD,
                                             float4 cw, unsigned short* dst) {
    unsigned ua[2] = {uA.x, uA.y};
    unsigned ub[2] = {uB.x, uB.y};
    unsigned uc[2] = {uC.x, uC.y};
    unsigned ud[2] = {uD.x, uD.y};
    unsigned pk[2];
#pragma unroll
    for (int i = 0; i < 2; ++i) {
        f32x2 va = {blo(ua[i]), bhi(ua[i])};
        f32x2 vb = {blo(ub[i]), bhi(ub[i])};
        f32x2 vc = {blo(uc[i]), bhi(uc[i])};
        f32x2 vd = {blo(ud[i]), bhi(ud[i])};
        f32x2 v = cw.x * va + cw.y * vb + cw.z * vc + cw.w * vd;
        pk[i] = pk2(v[0], v[1]);
    }
    *(uint2*)dst = make_uint2(pk[0], pk[1]);
}

// ============ Fused prep kernel (block-specialized) ============
// b==0          : offset net -> ipar/fpar
// b in [1,145)  : A2f  (deform A, MFMA-fragment order)  36864 slots
// b in [145,289): Awf  (tconv A, MFMA-fragment order)   36864 slots
// b in [289,801): xp   (x -> channels-last padded bf16)
__global__ __launch_bounds__(256) void k_prep(const float* __restrict__ x,
                                              const float* __restrict__ lat,
                                              const float* __restrict__ tw,
                                              const float* __restrict__ w1,
                                              const float* __restrict__ b1,
                                              const float* __restrict__ w2,
                                              const float* __restrict__ b2,
                                              unsigned short* __restrict__ xp,
                                              unsigned short* __restrict__ A2f,
                                              unsigned short* __restrict__ Awf,
                                              int* __restrict__ ipar,
                                              float* __restrict__ fpar) {
    __shared__ float sm[8420];
    int b = blockIdx.x, t = threadIdx.x;
    if (b == 0) {
        for (int i = t; i < 8192; i += 256) sm[(i >> 7) * 129 + (i & 127)] = w1[i * 9 + 4];
        __syncthreads();
        if (t < 128) {
            int n = t >> 6, o = t & 63;
            float s = b1[o];
            const float* ln = lat + n * 128;
#pragma unroll 8
            for (int c = 0; c < 128; ++c) s += ln[c] * sm[o * 129 + c];
            sm[8256 + t] = fmaxf(s, 0.f);
        }
        __syncthreads();
        if (t < 36) {
            int n = t / 18, j = t % 18;
            float s = b2[j];
            for (int o = 0; o < 64; ++o) s += sm[8256 + n * 64 + o] * w2[(j * 64 + o) * 9 + 4];
            float ov = tanhf(s);
            ov = fminf(fmaxf(ov, -0.999999f), 0.999999f);
            sm[8384 + t] = ov;
        }
        __syncthreads();
        if (t < 36) {
            int n = t / 18, j = t % 18;
            int tap = j >> 1, d = j & 1;
            float ov = sm[8384 + t];
            float fl = floorf(ov);
            int kc = d ? (tap % 3) : (tap / 3);
            ipar[(n * 9 + tap) * 2 + d] = kc - 1 + (int)fl;
            fpar[(n * 9 + tap) * 2 + d] = ov - fl;
        }
    } else if (b < 145) {
        // A2f slot = ((k*4 + w)*4 + mi)*64 + l ; elem = slot*8 + j
        int slot = (b - 1) * 256 + t;
        int l = slot & 63;
        int mi = (slot >> 6) & 3;
        int w = (slot >> 8) & 3;
        int k = slot >> 10;                 // 0..35
        int row = w * 64 + mi * 16 + (l & 15);
        int kq = l >> 4;
        unsigned short v[8];
#pragma unroll
        for (int j = 0; j < 8; ++j) {
            int kcol = k * 32 + kq * 8 + j;  // < 1152
            int tap = kcol >> 7, c = kcol & 127;
            v[j] = f2bf(tw[(row * 128 + c) * 9 + tap]);
        }
        unsigned p0 = (unsigned)v[0] | ((unsigned)v[1] << 16);
        unsigned p1 = (unsigned)v[2] | ((unsigned)v[3] << 16);
        unsigned p2 = (unsigned)v[4] | ((unsigned)v[5] << 16);
        unsigned p3 = (unsigned)v[6] | ((unsigned)v[7] << 16);
        *(uint4*)(A2f + slot * 8) = make_uint4(p0, p1, p2, p3);
    } else if (b < 289) {
        // Awf slot = ((k*2 + wm)*4 + mi)*64 + l
        int slot = (b - 145) * 256 + t;
        int l = slot & 63;
        int mi = (slot >> 6) & 3;
        int wm = (slot >> 8) & 1;
        int k = slot >> 9;                  // 0..71
        int row = wm * 64 + mi * 16 + (l & 15);
        int kq = l >> 4;
        unsigned short v[8];
#pragma unroll
        for (int j = 0; j < 8; ++j) {
            int kcol = k * 32 + kq * 8 + j;  // < 2304
            int t9 = kcol >> 8, ci = kcol & 255;
            int ky = t9 / 3, kx = t9 - ky * 3;
            v[j] = f2bf(tw[(ci * 128 + row) * 9 + (2 - ky) * 3 + (2 - kx)]);
        }
        unsigned p0 = (unsigned)v[0] | ((unsigned)v[1] << 16);
        unsigned p1 = (unsigned)v[2] | ((unsigned)v[3] << 16);
        unsigned p2 = (unsigned)v[4] | ((unsigned)v[5] << 16);
        unsigned p3 = (unsigned)v[6] | ((unsigned)v[7] << 16);
        *(uint4*)(Awf + slot * 8) = make_uint4(p0, p1, p2, p3);
    } else {
        int bb = b - 289;
        int h = bb & 63, cq = (bb >> 6) & 3, n = bb >> 8;
        int c0 = cq * 64;
        {
            int wcol = t & 63, sub = t >> 6;
            for (int r = 0; r < 16; ++r) {
                int ci_l = r * 4 + sub;
                sm[ci_l * 65 + wcol] = x[((n * 256 + c0 + ci_l) * 64 + h) * 64 + wcol];
            }
        }
        __syncthreads();
        int wcol = t >> 2, cg = t & 3;
        unsigned short* dst = xp + (size_t)n * (65 * 65 * 256) + (h * 65 + wcol) * 256 + c0 + cg * 16;
        unsigned pk[8];
#pragma unroll
        for (int j = 0; j < 8; ++j)
            pk[j] = pk2(sm[(cg * 16 + 2 * j) * 65 + wcol], sm[(cg * 16 + 2 * j + 1) * 65 + wcol]);
        *(uint4*)dst = make_uint4(pk[0], pk[1], pk[2], pk[3]);
        *(uint4*)(dst + 8) = make_uint4(pk[4], pk[5], pk[6], pk[7]);
    }
}

// ============ tconv: parity-decomposed MFMA GEMM, N-tile 32, 1024 blocks ============
// block bits: b = yh(6) | xh(1) | n(1) | xpb(1) | phase(1)  (low bits interleave
// heavy/light parity classes across CUs for load balance)
__global__ __launch_bounds__(256) void k_tconv3(const unsigned short* __restrict__ xp,
                                                const unsigned short* __restrict__ Awf,
                                                unsigned short* __restrict__ upp) {
    __shared__ unsigned short Bs[2][32][40];
    __shared__ int st9[4];
    __shared__ int sbb[4];
    int t = threadIdx.x;
    int b = blockIdx.x;
    int phase = b & 1;
    int xpar = ((b >> 1) & 1) ^ phase;
    int n = (b >> 2) & 1;
    int xh = (b >> 3) & 1;
    int yh = b >> 4;                 // 0..63
    int y = yh * 2 + phase;
    const unsigned short* xpn = xp + (size_t)n * (65 * 65 * 256);

    int lane = t & 63, w = t >> 6;
    int col = lane & 15, q = lane >> 4;
    int wm = w >> 1, wn = w & 1;
    int px = t >> 3, cg = t & 7;
    int boff = px * 256 + cg * 4;

    int kys[2], kxs[2], nky, nkx;
    if (phase) { kys[0] = 0; kys[1] = 2; nky = 2; } else { kys[0] = 1; kys[1] = 1; nky = 1; }
    if (xpar)  { kxs[0] = 0; kxs[1] = 2; nkx = 2; } else { kxs[0] = 1; kxs[1] = 1; nkx = 1; }
    int nslots = nky * nkx;
    if (t < nslots) {
        int a1 = t / nkx, a2 = t % nkx;
        int ky = kys[a1], kx = kxs[a2];
        st9[t] = ky * 3 + kx;
        int d2 = (y + ky - 1) >> 1;
        int s = (xpar + kx - 1) >> 1;
        sbb[t] = (d2 * 65 + s + xh * 32) * 256;
    }
    int NT = nslots * 8;

    f32x4 acc[4];
#pragma unroll
    for (int mi = 0; mi < 4; ++mi) acc[mi] = (f32x4){0.f, 0.f, 0.f, 0.f};

    __syncthreads();   // st9/sbb visible

    const unsigned short* Afw = Awf + wm * 2048 + lane * 8;  // + k*4096 + mi*512
    s16x8 a_cur[4], a_nxt[4];

    // prologue: chunk 0
    {
        int kAw0 = st9[0] * 8;
        uint2 bv = *(const uint2*)(xpn + sbb[0] + boff);
        *(uint2*)&Bs[0][px][cg * 4] = bv;
#pragma unroll
        for (int mi = 0; mi < 4; ++mi)
            a_cur[mi] = *(const s16x8*)(Afw + kAw0 * 4096 + mi * 512);
    }
    __syncthreads();

    for (int cc = 0; cc < NT; ++cc) {
        int cc1 = cc + 1;
        uint2 bv;
        if (cc1 < NT) {
            int slot1 = cc1 >> 3, cb1 = cc1 & 7;
            bv = *(const uint2*)(xpn + sbb[slot1] + cb1 * 32 + boff);
            int kAw1 = st9[slot1] * 8 + cb1;
#pragma unroll
            for (int mi = 0; mi < 4; ++mi)
                a_nxt[mi] = *(const s16x8*)(Afw + kAw1 * 4096 + mi * 512);
        }
        s16x8 bb = *(const s16x8*)&Bs[cc & 1][wn * 16 + col][q * 8];
#pragma unroll
        for (int mi = 0; mi < 4; ++mi)
            acc[mi] = __builtin_amdgcn_mfma_f32_16x16x32_bf16(a_cur[mi], bb, acc[mi], 0, 0, 0);
        if (cc1 < NT) {
            *(uint2*)&Bs[cc1 & 1][px][cg * 4] = bv;
#pragma unroll
            for (int mi = 0; mi < 4; ++mi) a_cur[mi] = a_nxt[mi];
        }
        __syncthreads();
    }

    unsigned short* uppn = upp + (size_t)n * (132 * 132 * 128);
#pragma unroll
    for (int mi = 0; mi < 4; ++mi) {
        int co = wm * 64 + mi * 16 + q * 4;
        int p64 = xh * 32 + wn * 16 + col;
        int xg = 2 * p64 + xpar;
        unsigned short* p = uppn + ((y + 2) * 132 + (xg + 2)) * 128 + co;
        unsigned lo = pk2(acc[mi][0], acc[mi][1]);
        unsigned hi = pk2(acc[mi][2], acc[mi][3]);
        *(uint2*)p = make_uint2(lo, hi);
    }
}

// ============ deform: MFMA GEMM, N-tile 32, 1024 blocks (4 blocks/CU) ============
__global__ __launch_bounds__(256) void k_deform3(const unsigned short* __restrict__ upp,
                                                 const unsigned short* __restrict__ A2f,
                                                 const int* __restrict__ ipar,
                                                 const float* __restrict__ fpar,
                                                 float* __restrict__ out) {
    __shared__ unsigned short Bs[2][32][40];
    __shared__ int sbase[9];
    __shared__ float4 swt[9];
    int t = threadIdx.x;
    int b = blockIdx.x;
    int xcd = b & 7, j = b >> 3;          // j in [0,128)
    int n = xcd >> 2, band = xcd & 3;
    int y = band * 32 + (j & 31);
    int tx0 = (j >> 5) * 32;              // 4 strips of 32
    const unsigned short* uppn = upp + (size_t)n * (132 * 132 * 128);

    int lane = t & 63, w = t >> 6;
    int col = lane & 15, q = lane >> 4;
    int px = t >> 3, cg = t & 7;
    int boff = px * 128 + cg * 4;

    if (t < 9) {
        int iy = ipar[(n * 9 + t) * 2 + 0], ix = ipar[(n * 9 + t) * 2 + 1];
        float fy = fpar[(n * 9 + t) * 2 + 0], fx = fpar[(n * 9 + t) * 2 + 1];
        sbase[t] = ((y + 2 + iy) * 132 + (tx0 + 2 + ix)) * 128;
        swt[t] = make_float4((1.f - fy) * (1.f - fx), (1.f - fy) * fx, fy * (1.f - fx), fy * fx);
    }

    f32x4 acc[4][2];
#pragma unroll
    for (int mi = 0; mi < 4; ++mi)
#pragma unroll
        for (int ni = 0; ni < 2; ++ni) acc[mi][ni] = (f32x4){0.f, 0.f, 0.f, 0.f};

    __syncthreads();   // sbase/swt visible

    const unsigned short* Afw = A2f + w * 2048 + lane * 8;   // + k*8192 + mi*512
    s16x8 a_cur[4], a_nxt[4];

    // prologue: chunk 0 (tap 0, cb 0)
    {
        const unsigned short* p = uppn + sbase[0] + boff;
        uint2 uA = *(const uint2*)p;
        uint2 uB = *(const uint2*)(p + 128);
        uint2 uC = *(const uint2*)(p + 16896);
        uint2 uD = *(const uint2*)(p + 17024);
        blend_store2(uA, uB, uC, uD, swt[0], &Bs[0][px][cg * 4]);
#pragma unroll
        for (int mi = 0; mi < 4; ++mi)
            a_cur[mi] = *(const s16x8*)(Afw + mi * 512);
    }
    __syncthreads();

#pragma unroll 2
    for (int k = 0; k < 36; ++k) {
        int k1 = k + 1;
        uint2 uA, uB, uC, uD;
        float4 cw;
        if (k1 < 36) {
            int t1 = k1 >> 2, cb1 = (k1 & 3) * 32;
            int base = sbase[t1];
            cw = swt[t1];
            const unsigned short* p = uppn + base + cb1 + boff;
            uA = *(const uint2*)p;
            uB = *(const uint2*)(p + 128);
            uC = *(const uint2*)(p + 16896);
            uD = *(const uint2*)(p + 17024);
#pragma unroll
            for (int mi = 0; mi < 4; ++mi)
                a_nxt[mi] = *(const s16x8*)(Afw + k1 * 8192 + mi * 512);
        }
        s16x8 bb[2];
#pragma unroll
        for (int ni = 0; ni < 2; ++ni)
            bb[ni] = *(const s16x8*)&Bs[k & 1][ni * 16 + col][q * 8];
#pragma unroll
        for (int mi = 0; mi < 4; ++mi)
#pragma unroll
            for (int ni = 0; ni < 2; ++ni)
                acc[mi][ni] = __builtin_amdgcn_mfma_f32_16x16x32_bf16(a_cur[mi], bb[ni], acc[mi][ni], 0, 0, 0);
        if (k1 < 36) {
            blend_store2(uA, uB, uC, uD, cw, &Bs[k1 & 1][px][cg * 4]);
#pragma unroll
            for (int mi = 0; mi < 4; ++mi) a_cur[mi] = a_nxt[mi];
        }
        __syncthreads();
    }

#pragma unroll
    for (int mi = 0; mi < 4; ++mi)
#pragma unroll
        for (int ni = 0; ni < 2; ++ni) {
            int o = w * 64 + mi * 16 + q * 4;
            int xg = tx0 + ni * 16 + col;
            float* p = out + (((size_t)(n * 256 + o)) * 128 + y) * 128 + xg;
            p[0]         = acc[mi][ni][0];
            p[16384]     = acc[mi][ni][1];
            p[2 * 16384] = acc[mi][ni][2];
            p[3 * 16384] = acc[mi][ni][3];
        }
}

extern "C" void kernel_launch(void* const* d_in, const int* in_sizes, int n_in,
                              void* d_out, int out_size, void* d_ws, size_t ws_size,
                              hipStream_t stream) {
    const float* x   = (const float*)d_in[0];
    const float* lat = (const float*)d_in[1];
    const float* tw  = (const float*)d_in[2];
    const float* w1  = (const float*)d_in[3];
    const float* b1  = (const float*)d_in[4];
    const float* w2  = (const float*)d_in[5];
    const float* b2  = (const float*)d_in[6];
    float* out = (float*)d_out;

    char* ws = (char*)d_ws;
    // upp bf16 halo2: 2*132*132*128*2 = 8,921,088 @ 0
    // xp  bf16 pad+1: 2*65*65*256*2   = 4,326,400 @ 8,921,088   (one memset covers both)
    // A2f: 294912*2 = 589,824 @ 13,247,488
    // Awf: 294912*2 = 589,824 @ 13,837,312
    unsigned short* upp = (unsigned short*)ws;
    unsigned short* xp  = (unsigned short*)(ws + 8921088);
    unsigned short* A2f = (unsigned short*)(ws + 13247488);
    unsigned short* Awf = (unsigned short*)(ws + 13837312);
    int*   ipar         = (int*)(ws + 14427136);
    float* fpar         = (float*)(ws + 14427424);

    hipMemsetAsync(ws, 0, 13247488, stream);
    k_prep<<<801, 256, 0, stream>>>(x, lat, tw, w1, b1, w2, b2, xp, A2f, Awf, ipar, fpar);
    k_tconv3<<<1024, 256, 0, stream>>>(xp, Awf, upp);
    k_deform3<<<1024, 256, 0, stream>>>(upp, A2f, ipar, fpar, out);
}

// Round 2
// 146.302 us; speedup vs baseline: 1.0832x; 1.0832x over previous
//
#include <hip/hip_runtime.h>
#include <hip/hip_bf16.h>
#include <math.h>

typedef __attribute__((ext_vector_type(8))) short s16x8;
typedef __attribute__((ext_vector_type(4))) float f32x4;
typedef __attribute__((ext_vector_type(2))) float f32x2;

__device__ __forceinline__ unsigned short f2bf(float f) {
    union { float f; unsigned int u; } v; v.f = f;
    unsigned int u = v.u + 0x7FFFu + ((v.u >> 16) & 1u);
    return (unsigned short)(u >> 16);
}
__device__ __forceinline__ unsigned pk2(float lo, float hi) {
    __hip_bfloat162 h = __float22bfloat162_rn(make_float2(lo, hi));
    union { __hip_bfloat162 h; unsigned u; } v; v.h = h;
    return v.u;
}
__device__ __forceinline__ float blo(unsigned u) {
    union { unsigned u; float f; } v; v.u = u << 16; return v.f;
}
__device__ __forceinline__ float bhi(unsigned u) {
    union { unsigned u; float f; } v; v.u = u & 0xffff0000u; return v.f;
}

// Raw barrier: LDS drained (cross-wave visibility of ds_write), but global
// loads in flight (our prefetch) intentionally NOT drained -- __syncthreads
// would emit s_waitcnt vmcnt(0) and kill the 2-deep prefetch.
#define BARRIER() do { asm volatile("s_waitcnt lgkmcnt(0)" ::: "memory"); \
                       __builtin_amdgcn_s_barrier(); } while (0)

// Blend 4 corner uint4s (8 bf16 channels each) into one packed uint4, store to LDS.
__device__ __forceinline__ void blend_store(uint4 uA, uint4 uB, uint4 uC, uint4 uD,
                                            float4 cw, unsigned short* dst) {
    unsigned ua[4] = {uA.x, uA.y, uA.z, uA.w};
    unsigned ub[4] = {uB.x, uB.y, uB.z, uB.w};
    unsigned uc[4] = {uC.x, uC.y, uC.z, uC.w};
    unsigned ud[4] = {uD.x, uD.y, uD.z, uD.w};
    unsigned pk[4];
#pragma unroll
    for (int i = 0; i < 4; ++i) {
        f32x2 va = {blo(ua[i]), bhi(ua[i])};
        f32x2 vb = {blo(ub[i]), bhi(ub[i])};
        f32x2 vc = {blo(uc[i]), bhi(uc[i])};
        f32x2 vd = {blo(ud[i]), bhi(ud[i])};
        f32x2 v = cw.x * va + cw.y * vb + cw.z * vc + cw.w * vd;
        pk[i] = pk2(v[0], v[1]);
    }
    *(uint4*)dst = make_uint4(pk[0], pk[1], pk[2], pk[3]);
}

struct C4 { uint4 A, B, C, D; };

__device__ __forceinline__ C4 ldc(const unsigned short* p) {
    C4 r;
    r.A = *(const uint4*)p;
    r.B = *(const uint4*)(p + 128);
    r.C = *(const uint4*)(p + 16896);
    r.D = *(const uint4*)(p + 17024);
    return r;
}

// ============ Fused prep kernel (block-specialized) ============
__global__ __launch_bounds__(256) void k_prep(const float* __restrict__ x,
                                              const float* __restrict__ lat,
                                              const float* __restrict__ tw,
                                              const float* __restrict__ w1,
                                              const float* __restrict__ b1,
                                              const float* __restrict__ w2,
                                              const float* __restrict__ b2,
                                              unsigned short* __restrict__ xp,
                                              unsigned short* __restrict__ A2f,
                                              unsigned short* __restrict__ Awf,
                                              int* __restrict__ ipar,
                                              float* __restrict__ fpar) {
    __shared__ float sm[8420];
    int b = blockIdx.x, t = threadIdx.x;
    if (b == 0) {
        for (int i = t; i < 8192; i += 256) sm[(i >> 7) * 129 + (i & 127)] = w1[i * 9 + 4];
        __syncthreads();
        if (t < 128) {
            int n = t >> 6, o = t & 63;
            float s = b1[o];
            const float* ln = lat + n * 128;
#pragma unroll 8
            for (int c = 0; c < 128; ++c) s += ln[c] * sm[o * 129 + c];
            sm[8256 + t] = fmaxf(s, 0.f);
        }
        __syncthreads();
        if (t < 36) {
            int n = t / 18, j = t % 18;
            float s = b2[j];
            for (int o = 0; o < 64; ++o) s += sm[8256 + n * 64 + o] * w2[(j * 64 + o) * 9 + 4];
            float ov = tanhf(s);
            ov = fminf(fmaxf(ov, -0.999999f), 0.999999f);
            sm[8384 + t] = ov;
        }
        __syncthreads();
        if (t < 36) {
            int n = t / 18, j = t % 18;
            int tap = j >> 1, d = j & 1;
            float ov = sm[8384 + t];
            float fl = floorf(ov);
            int kc = d ? (tap % 3) : (tap / 3);
            ipar[(n * 9 + tap) * 2 + d] = kc - 1 + (int)fl;
            fpar[(n * 9 + tap) * 2 + d] = ov - fl;
        }
    } else if (b < 145) {
        int slot = (b - 1) * 256 + t;
        int l = slot & 63;
        int mi = (slot >> 6) & 3;
        int w = (slot >> 8) & 3;
        int k = slot >> 10;                 // 0..35
        int row = w * 64 + mi * 16 + (l & 15);
        int kq = l >> 4;
        unsigned short v[8];
#pragma unroll
        for (int j = 0; j < 8; ++j) {
            int kcol = k * 32 + kq * 8 + j;  // < 1152
            int tap = kcol >> 7, c = kcol & 127;
            v[j] = f2bf(tw[(row * 128 + c) * 9 + tap]);
        }
        unsigned p0 = (unsigned)v[0] | ((unsigned)v[1] << 16);
        unsigned p1 = (unsigned)v[2] | ((unsigned)v[3] << 16);
        unsigned p2 = (unsigned)v[4] | ((unsigned)v[5] << 16);
        unsigned p3 = (unsigned)v[6] | ((unsigned)v[7] << 16);
        *(uint4*)(A2f + slot * 8) = make_uint4(p0, p1, p2, p3);
    } else if (b < 289) {
        int slot = (b - 145) * 256 + t;
        int l = slot & 63;
        int mi = (slot >> 6) & 3;
        int wm = (slot >> 8) & 1;
        int k = slot >> 9;                  // 0..71
        int row = wm * 64 + mi * 16 + (l & 15);
        int kq = l >> 4;
        unsigned short v[8];
#pragma unroll
        for (int j = 0; j < 8; ++j) {
            int kcol = k * 32 + kq * 8 + j;  // < 2304
            int t9 = kcol >> 8, ci = kcol & 255;
            int ky = t9 / 3, kx = t9 - ky * 3;
            v[j] = f2bf(tw[(ci * 128 + row) * 9 + (2 - ky) * 3 + (2 - kx)]);
        }
        unsigned p0 = (unsigned)v[0] | ((unsigned)v[1] << 16);
        unsigned p1 = (unsigned)v[2] | ((unsigned)v[3] << 16);
        unsigned p2 = (unsigned)v[4] | ((unsigned)v[5] << 16);
        unsigned p3 = (unsigned)v[6] | ((unsigned)v[7] << 16);
        *(uint4*)(Awf + slot * 8) = make_uint4(p0, p1, p2, p3);
    } else {
        int bb = b - 289;
        int h = bb & 63, cq = (bb >> 6) & 3, n = bb >> 8;
        int c0 = cq * 64;
        {
            int wcol = t & 63, sub = t >> 6;
            for (int r = 0; r < 16; ++r) {
                int ci_l = r * 4 + sub;
                sm[ci_l * 65 + wcol] = x[((n * 256 + c0 + ci_l) * 64 + h) * 64 + wcol];
            }
        }
        __syncthreads();
        int wcol = t >> 2, cg = t & 3;
        unsigned short* dst = xp + (size_t)n * (65 * 65 * 256) + (h * 65 + wcol) * 256 + c0 + cg * 16;
        unsigned pk[8];
#pragma unroll
        for (int j = 0; j < 8; ++j)
            pk[j] = pk2(sm[(cg * 16 + 2 * j) * 65 + wcol], sm[(cg * 16 + 2 * j + 1) * 65 + wcol]);
        *(uint4*)dst = make_uint4(pk[0], pk[1], pk[2], pk[3]);
        *(uint4*)(dst + 8) = make_uint4(pk[4], pk[5], pk[6], pk[7]);
    }
}

// ============ tconv: parity-decomposed MFMA GEMM, 64-px tiles, prefetch-2 ============
// block bits: b = yh(6) | n(1) | xpb(1) | phase(1)  -- parity classes (NT=8/16/16/32)
// on the LOW bits so heavy and light blocks interleave across CUs.
__global__ __launch_bounds__(256) void k_tconv3(const unsigned short* __restrict__ xp,
                                                const unsigned short* __restrict__ Awf,
                                                unsigned short* __restrict__ upp) {
    __shared__ unsigned short Bs[2][64][40];
    __shared__ int st9[4];
    __shared__ int sbb[4];
    int t = threadIdx.x;
    int b = blockIdx.x;
    int phase = b & 1;
    int xpar = ((b >> 1) & 1) ^ phase;
    int n = (b >> 2) & 1;
    int yh = b >> 3;                 // 0..63
    int y = yh * 2 + phase;
    const unsigned short* xpn = xp + (size_t)n * (65 * 65 * 256);

    int lane = t & 63, w = t >> 6;
    int col = lane & 15, q = lane >> 4;
    int wm = w >> 1, wn = w & 1;
    int bx = t >> 2, bcg = t & 3;
    int boff = bx * 256 + bcg * 8;

    int kys[2], kxs[2], nky, nkx;
    if (phase) { kys[0] = 0; kys[1] = 2; nky = 2; } else { kys[0] = 1; kys[1] = 1; nky = 1; }
    if (xpar)  { kxs[0] = 0; kxs[1] = 2; nkx = 2; } else { kxs[0] = 1; kxs[1] = 1; nkx = 1; }
    int nslots = nky * nkx;
    if (t < nslots) {
        int a1 = t / nkx, a2 = t % nkx;
        int ky = kys[a1], kx = kxs[a2];
        st9[t] = ky * 3 + kx;
        int d2 = (y + ky - 1) >> 1;
        int s = (xpar + kx - 1) >> 1;
        sbb[t] = (d2 * 65 + s) * 256;
    }
    int NT = nslots * 8;

    f32x4 acc[4][2];
#pragma unroll
    for (int mi = 0; mi < 4; ++mi)
#pragma unroll
        for (int ni = 0; ni < 2; ++ni) acc[mi][ni] = (f32x4){0.f, 0.f, 0.f, 0.f};

    __syncthreads();   // st9/sbb visible

    const unsigned short* Afw = Awf + wm * 2048 + lane * 8;  // + kA*4096 + mi*512
    s16x8 aC[4], aN[4];
    uint4 R0, R1;

#define TCADDR(cc) (xpn + sbb[(cc) >> 3] + ((cc) & 7) * 32 + boff)

    // prologue: chunks 0 and 1 in flight; chunk 0 staged
    {
        R0 = *(const uint4*)TCADDR(0);
        R1 = *(const uint4*)TCADDR(1);
        const unsigned short* ap = Afw + st9[0] * 8 * 4096;
#pragma unroll
        for (int mi = 0; mi < 4; ++mi) aC[mi] = *(const s16x8*)(ap + mi * 512);
        *(uint4*)&Bs[0][bx][bcg * 8] = R0;
    }
    BARRIER();

#define TC_ITER(CC, BUF, AC, AN, RC, RF)                                         \
    {                                                                            \
        int c_ = (CC);                                                           \
        if (c_ + 2 < NT) RF = *(const uint4*)TCADDR(c_ + 2);                     \
        if (c_ + 1 < NT) {                                                       \
            int s1_ = (c_ + 1) >> 3, cb1_ = (c_ + 1) & 7;                        \
            const unsigned short* ap_ = Afw + (st9[s1_] * 8 + cb1_) * 4096;      \
            _Pragma("unroll")                                                    \
            for (int mi = 0; mi < 4; ++mi) AN[mi] = *(const s16x8*)(ap_ + mi * 512); \
        }                                                                        \
        s16x8 bb[2];                                                             \
        _Pragma("unroll")                                                        \
        for (int ni = 0; ni < 2; ++ni)                                           \
            bb[ni] = *(const s16x8*)&Bs[BUF][wn * 32 + ni * 16 + col][q * 8];    \
        _Pragma("unroll")                                                        \
        for (int mi = 0; mi < 4; ++mi)                                           \
            _Pragma("unroll")                                                    \
            for (int ni = 0; ni < 2; ++ni)                                       \
                acc[mi][ni] = __builtin_amdgcn_mfma_f32_16x16x32_bf16(AC[mi], bb[ni], acc[mi][ni], 0, 0, 0); \
        if (c_ + 1 < NT) *(uint4*)&Bs[BUF ^ 1][bx][bcg * 8] = RC;                \
        BARRIER();                                                               \
    }

    for (int cc = 0; cc < NT; cc += 2) {
        TC_ITER(cc,     0, aC, aN, R1, R0);
        TC_ITER(cc + 1, 1, aN, aC, R0, R1);
    }
#undef TC_ITER
#undef TCADDR

    unsigned short* uppn = upp + (size_t)n * (132 * 132 * 128);
#pragma unroll
    for (int mi = 0; mi < 4; ++mi)
#pragma unroll
        for (int ni = 0; ni < 2; ++ni) {
            int co = wm * 64 + mi * 16 + q * 4;
            int p64 = wn * 32 + ni * 16 + col;
            int xg = 2 * p64 + xpar;
            unsigned short* p = uppn + ((y + 2) * 132 + (xg + 2)) * 128 + co;
            unsigned lo = pk2(acc[mi][ni][0], acc[mi][ni][1]);
            unsigned hi = pk2(acc[mi][ni][2], acc[mi][ni][3]);
            *(uint2*)p = make_uint2(lo, hi);
        }
}

// ============ deform: MFMA GEMM, 64-px tiles, prefetch-2 corner loads ============
__global__ __launch_bounds__(256) void k_deform3(const unsigned short* __restrict__ upp,
                                                 const unsigned short* __restrict__ A2f,
                                                 const int* __restrict__ ipar,
                                                 const float* __restrict__ fpar,
                                                 float* __restrict__ out) {
    __shared__ unsigned short Bs[2][64][40];
    __shared__ int sbase[9];
    __shared__ float4 swt[9];
    int t = threadIdx.x;
    int b = blockIdx.x;
    int xcd = b & 7, j = b >> 3;          // j in [0,64)
    int n = xcd >> 2, band = xcd & 3;
    int y = band * 32 + (j & 31);
    int tx0 = (j >> 5) * 64;              // 2 strips of 64
    const unsigned short* uppn = upp + (size_t)n * (132 * 132 * 128);

    int lane = t & 63, w = t >> 6;
    int col = lane & 15, q = lane >> 4;
    int bx = t >> 2, bcg = t & 3;
    int boff = bx * 128 + bcg * 8;

    if (t < 9) {
        int iy = ipar[(n * 9 + t) * 2 + 0], ix = ipar[(n * 9 + t) * 2 + 1];
        float fy = fpar[(n * 9 + t) * 2 + 0], fx = fpar[(n * 9 + t) * 2 + 1];
        sbase[t] = ((y + 2 + iy) * 132 + (tx0 + 2 + ix)) * 128;
        swt[t] = make_float4((1.f - fy) * (1.f - fx), (1.f - fy) * fx, fy * (1.f - fx), fy * fx);
    }

    f32x4 acc[4][4];
#pragma unroll
    for (int mi = 0; mi < 4; ++mi)
#pragma unroll
        for (int ni = 0; ni < 4; ++ni) acc[mi][ni] = (f32x4){0.f, 0.f, 0.f, 0.f};

    __syncthreads();   // sbase/swt visible

    const unsigned short* Afw = A2f + w * 2048 + lane * 8;   // + k*8192 + mi*512
    s16x8 aC[4], aN[4];
    C4 R0, R1;

#define DCADDR(k) (uppn + sbase[(k) >> 2] + ((k) & 3) * 32 + boff)

    // prologue: chunks 0 and 1 corner data in flight; chunk 0 blended+staged
    {
        R0 = ldc(DCADDR(0));
        R1 = ldc(DCADDR(1));
#pragma unroll
        for (int mi = 0; mi < 4; ++mi) aC[mi] = *(const s16x8*)(Afw + mi * 512);
        blend_store(R0.A, R0.B, R0.C, R0.D, swt[0], &Bs[0][bx][bcg * 8]);
    }
    BARRIER();

#define DEF_ITER(KK, BUF, AC, AN, RC, RF)                                        \
    {                                                                            \
        int k_ = (KK);                                                           \
        if (k_ + 2 < 36) RF = ldc(DCADDR(k_ + 2));                               \
        if (k_ + 1 < 36) {                                                       \
            const unsigned short* ap_ = Afw + (k_ + 1) * 8192;                   \
            _Pragma("unroll")                                                    \
            for (int mi = 0; mi < 4; ++mi) AN[mi] = *(const s16x8*)(ap_ + mi * 512); \
        }                                                                        \
        s16x8 bb[4];                                                             \
        _Pragma("unroll")                                                        \
        for (int ni = 0; ni < 4; ++ni)                                           \
            bb[ni] = *(const s16x8*)&Bs[BUF][ni * 16 + col][q * 8];              \
        _Pragma("unroll")                                                        \
        for (int mi = 0; mi < 4; ++mi)                                           \
            _Pragma("unroll")                                                    \
            for (int ni = 0; ni < 4; ++ni)                                       \
                acc[mi][ni] = __builtin_amdgcn_mfma_f32_16x16x32_bf16(AC[mi], bb[ni], acc[mi][ni], 0, 0, 0); \
        if (k_ + 1 < 36)                                                         \
            blend_store(RC.A, RC.B, RC.C, RC.D, swt[(k_ + 1) >> 2],              \
                        &Bs[BUF ^ 1][bx][bcg * 8]);                              \
        BARRIER();                                                               \
    }

    for (int kk = 0; kk < 36; kk += 2) {
        DEF_ITER(kk,     0, aC, aN, R1, R0);
        DEF_ITER(kk + 1, 1, aN, aC, R0, R1);
    }
#undef DEF_ITER
#undef DCADDR

#pragma unroll
    for (int mi = 0; mi < 4; ++mi)
#pragma unroll
        for (int ni = 0; ni < 4; ++ni) {
            int o = w * 64 + mi * 16 + q * 4;
            int xg = tx0 + ni * 16 + col;
            float* p = out + (((size_t)(n * 256 + o)) * 128 + y) * 128 + xg;
            p[0]         = acc[mi][ni][0];
            p[16384]     = acc[mi][ni][1];
            p[2 * 16384] = acc[mi][ni][2];
            p[3 * 16384] = acc[mi][ni][3];
        }
}

extern "C" void kernel_launch(void* const* d_in, const int* in_sizes, int n_in,
                              void* d_out, int out_size, void* d_ws, size_t ws_size,
                              hipStream_t stream) {
    const float* x   = (const float*)d_in[0];
    const float* lat = (const float*)d_in[1];
    const float* tw  = (const float*)d_in[2];
    const float* w1  = (const float*)d_in[3];
    const float* b1  = (const float*)d_in[4];
    const float* w2  = (const float*)d_in[5];
    const float* b2  = (const float*)d_in[6];
    float* out = (float*)d_out;

    char* ws = (char*)d_ws;
    // upp bf16 halo2: 2*132*132*128*2 = 8,921,088 @ 0
    // xp  bf16 pad+1: 2*65*65*256*2   = 4,326,400 @ 8,921,088   (one memset covers both)
    // A2f: 294912*2 = 589,824 @ 13,247,488
    // Awf: 294912*2 = 589,824 @ 13,837,312
    unsigned short* upp = (unsigned short*)ws;
    unsigned short* xp  = (unsigned short*)(ws + 8921088);
    unsigned short* A2f = (unsigned short*)(ws + 13247488);
    unsigned short* Awf = (unsigned short*)(ws + 13837312);
    int*   ipar         = (int*)(ws + 14427136);
    float* fpar         = (float*)(ws + 14427424);

    hipMemsetAsync(ws, 0, 13247488, stream);
    k_prep<<<801, 256, 0, stream>>>(x, lat, tw, w1, b1, w2, b2, xp, A2f, Awf, ipar, fpar);
    k_tconv3<<<512, 256, 0, stream>>>(xp, Awf, upp);
    k_deform3<<<512, 256, 0, stream>>>(upp, A2f, ipar, fpar, out);
}

// Round 3
// 142.586 us; speedup vs baseline: 1.1114x; 1.0261x over previous
//
#include <hip/hip_runtime.h>
#include <hip/hip_bf16.h>
#include <math.h>

typedef __attribute__((ext_vector_type(8))) short s16x8;
typedef __attribute__((ext_vector_type(4))) float f32x4;
typedef __attribute__((ext_vector_type(2))) float f32x2;

__device__ __forceinline__ unsigned short f2bf(float f) {
    union { float f; unsigned int u; } v; v.f = f;
    unsigned int u = v.u + 0x7FFFu + ((v.u >> 16) & 1u);
    return (unsigned short)(u >> 16);
}
__device__ __forceinline__ unsigned pk2(float lo, float hi) {
    __hip_bfloat162 h = __float22bfloat162_rn(make_float2(lo, hi));
    union { __hip_bfloat162 h; unsigned u; } v; v.h = h;
    return v.u;
}
__device__ __forceinline__ float blo(unsigned u) {
    union { unsigned u; float f; } v; v.u = u << 16; return v.f;
}
__device__ __forceinline__ float bhi(unsigned u) {
    union { unsigned u; float f; } v; v.u = u & 0xffff0000u; return v.f;
}

// Raw barrier: LDS drained (cross-wave visibility of ds_write), but global
// loads in flight (prefetch) intentionally NOT drained.
#define BARRIER() do { asm volatile("s_waitcnt lgkmcnt(0)" ::: "memory"); \
                       __builtin_amdgcn_s_barrier(); } while (0)

// Blend 4 corner uint4s (8 bf16 channels each) into one packed uint4, store to LDS.
__device__ __forceinline__ void blend_store(uint4 uA, uint4 uB, uint4 uC, uint4 uD,
                                            float4 cw, unsigned short* dst) {
    unsigned ua[4] = {uA.x, uA.y, uA.z, uA.w};
    unsigned ub[4] = {uB.x, uB.y, uB.z, uB.w};
    unsigned uc[4] = {uC.x, uC.y, uC.z, uC.w};
    unsigned ud[4] = {uD.x, uD.y, uD.z, uD.w};
    unsigned pk[4];
#pragma unroll
    for (int i = 0; i < 4; ++i) {
        f32x2 va = {blo(ua[i]), bhi(ua[i])};
        f32x2 vb = {blo(ub[i]), bhi(ub[i])};
        f32x2 vc = {blo(uc[i]), bhi(uc[i])};
        f32x2 vd = {blo(ud[i]), bhi(ud[i])};
        f32x2 v = cw.x * va + cw.y * vb + cw.z * vc + cw.w * vd;
        pk[i] = pk2(v[0], v[1]);
    }
    *(uint4*)dst = make_uint4(pk[0], pk[1], pk[2], pk[3]);
}

// ============ Fused prep kernel (block-specialized) ============
__global__ __launch_bounds__(256) void k_prep(const float* __restrict__ x,
                                              const float* __restrict__ lat,
                                              const float* __restrict__ tw,
                                              const float* __restrict__ w1,
                                              const float* __restrict__ b1,
                                              const float* __restrict__ w2,
                                              const float* __restrict__ b2,
                                              unsigned short* __restrict__ xp,
                                              unsigned short* __restrict__ A2f,
                                              unsigned short* __restrict__ Awf,
                                              int* __restrict__ ipar,
                                              float* __restrict__ fpar) {
    __shared__ float sm[8420];
    int b = blockIdx.x, t = threadIdx.x;
    if (b == 0) {
        for (int i = t; i < 8192; i += 256) sm[(i >> 7) * 129 + (i & 127)] = w1[i * 9 + 4];
        __syncthreads();
        if (t < 128) {
            int n = t >> 6, o = t & 63;
            float s = b1[o];
            const float* ln = lat + n * 128;
#pragma unroll 8
            for (int c = 0; c < 128; ++c) s += ln[c] * sm[o * 129 + c];
            sm[8256 + t] = fmaxf(s, 0.f);
        }
        __syncthreads();
        if (t < 36) {
            int n = t / 18, j = t % 18;
            float s = b2[j];
            for (int o = 0; o < 64; ++o) s += sm[8256 + n * 64 + o] * w2[(j * 64 + o) * 9 + 4];
            float ov = tanhf(s);
            ov = fminf(fmaxf(ov, -0.999999f), 0.999999f);
            sm[8384 + t] = ov;
        }
        __syncthreads();
        if (t < 36) {
            int n = t / 18, j = t % 18;
            int tap = j >> 1, d = j & 1;
            float ov = sm[8384 + t];
            float fl = floorf(ov);
            int kc = d ? (tap % 3) : (tap / 3);
            ipar[(n * 9 + tap) * 2 + d] = kc - 1 + (int)fl;
            fpar[(n * 9 + tap) * 2 + d] = ov - fl;
        }
    } else if (b < 145) {
        int slot = (b - 1) * 256 + t;
        int l = slot & 63;
        int mi = (slot >> 6) & 3;
        int w = (slot >> 8) & 3;
        int k = slot >> 10;                 // 0..35
        int row = w * 64 + mi * 16 + (l & 15);
        int kq = l >> 4;
        unsigned short v[8];
#pragma unroll
        for (int j = 0; j < 8; ++j) {
            int kcol = k * 32 + kq * 8 + j;  // < 1152
            int tap = kcol >> 7, c = kcol & 127;
            v[j] = f2bf(tw[(row * 128 + c) * 9 + tap]);
        }
        unsigned p0 = (unsigned)v[0] | ((unsigned)v[1] << 16);
        unsigned p1 = (unsigned)v[2] | ((unsigned)v[3] << 16);
        unsigned p2 = (unsigned)v[4] | ((unsigned)v[5] << 16);
        unsigned p3 = (unsigned)v[6] | ((unsigned)v[7] << 16);
        *(uint4*)(A2f + slot * 8) = make_uint4(p0, p1, p2, p3);
    } else if (b < 289) {
        int slot = (b - 145) * 256 + t;
        int l = slot & 63;
        int mi = (slot >> 6) & 3;
        int wm = (slot >> 8) & 1;
        int k = slot >> 9;                  // 0..71
        int row = wm * 64 + mi * 16 + (l & 15);
        int kq = l >> 4;
        unsigned short v[8];
#pragma unroll
        for (int j = 0; j < 8; ++j) {
            int kcol = k * 32 + kq * 8 + j;  // < 2304
            int t9 = kcol >> 8, ci = kcol & 255;
            int ky = t9 / 3, kx = t9 - ky * 3;
            v[j] = f2bf(tw[(ci * 128 + row) * 9 + (2 - ky) * 3 + (2 - kx)]);
        }
        unsigned p0 = (unsigned)v[0] | ((unsigned)v[1] << 16);
        unsigned p1 = (unsigned)v[2] | ((unsigned)v[3] << 16);
        unsigned p2 = (unsigned)v[4] | ((unsigned)v[5] << 16);
        unsigned p3 = (unsigned)v[6] | ((unsigned)v[7] << 16);
        *(uint4*)(Awf + slot * 8) = make_uint4(p0, p1, p2, p3);
    } else {
        int bb = b - 289;
        int h = bb & 63, cq = (bb >> 6) & 3, n = bb >> 8;
        int c0 = cq * 64;
        {
            int wcol = t & 63, sub = t >> 6;
            for (int r = 0; r < 16; ++r) {
                int ci_l = r * 4 + sub;
                sm[ci_l * 65 + wcol] = x[((n * 256 + c0 + ci_l) * 64 + h) * 64 + wcol];
            }
        }
        __syncthreads();
        int wcol = t >> 2, cg = t & 3;
        unsigned short* dst = xp + (size_t)n * (65 * 65 * 256) + (h * 65 + wcol) * 256 + c0 + cg * 16;
        unsigned pk[8];
#pragma unroll
        for (int j = 0; j < 8; ++j)
            pk[j] = pk2(sm[(cg * 16 + 2 * j) * 65 + wcol], sm[(cg * 16 + 2 * j + 1) * 65 + wcol]);
        *(uint4*)dst = make_uint4(pk[0], pk[1], pk[2], pk[3]);
        *(uint4*)(dst + 8) = make_uint4(pk[4], pk[5], pk[6], pk[7]);
    }
}

// ============ tconv: parity-decomposed MFMA GEMM, 2 K-chunks per barrier phase ============
// block bits: b = yh(6) | n(1) | xpb(1) | phase(1) -- parity classes (NT=8/16/16/32)
// on the LOW bits so heavy and light blocks interleave across CUs.
__global__ __launch_bounds__(256) void k_tconv3(const unsigned short* __restrict__ xp,
                                                const unsigned short* __restrict__ Awf,
                                                unsigned short* __restrict__ upp) {
    __shared__ unsigned short Bs[2][2][64][40];   // [buf][chunk][px][40]
    __shared__ int st9[4];
    __shared__ int sbb[4];
    int t = threadIdx.x;
    int b = blockIdx.x;
    int phase = b & 1;
    int xpar = ((b >> 1) & 1) ^ phase;
    int n = (b >> 2) & 1;
    int yh = b >> 3;                 // 0..63
    int y = yh * 2 + phase;
    const unsigned short* xpn = xp + (size_t)n * (65 * 65 * 256);

    int lane = t & 63, w = t >> 6;
    int col = lane & 15, q = lane >> 4;
    int wm = w >> 1, wn = w & 1;
    int bx = t >> 2, bcg = t & 3;
    int boff = bx * 256 + bcg * 8;

    int kys[2], kxs[2], nky, nkx;
    if (phase) { kys[0] = 0; kys[1] = 2; nky = 2; } else { kys[0] = 1; kys[1] = 1; nky = 1; }
    if (xpar)  { kxs[0] = 0; kxs[1] = 2; nkx = 2; } else { kxs[0] = 1; kxs[1] = 1; nkx = 1; }
    int nslots = nky * nkx;
    if (t < 4) {
        int tc = t < nslots ? t : 0;
        int a1 = (nkx == 2) ? (tc >> 1) : tc;
        int a2 = (nkx == 2) ? (tc & 1) : 0;
        int ky = kys[a1], kx = kxs[a2];
        st9[t] = ky * 3 + kx;
        int d2 = (y + ky - 1) >> 1;
        int s = (xpar + kx - 1) >> 1;
        sbb[t] = (d2 * 65 + s) * 256;
    }
    int NPAIR = nslots * 4;          // NT/2

    f32x4 acc[4][2];
#pragma unroll
    for (int mi = 0; mi < 4; ++mi)
#pragma unroll
        for (int ni = 0; ni < 2; ++ni) acc[mi][ni] = (f32x4){0.f, 0.f, 0.f, 0.f};

    __syncthreads();   // st9/sbb visible

    const unsigned short* Afw = Awf + wm * 2048 + lane * 8;  // + kA*4096 + mi*512
    s16x8 aC[2][4], aN[2][4];
    uint4 nb0, nb1;

    // prologue: pair 0 (chunks 0,1 of slot 0)
    {
        int t90 = st9[0], sb0 = sbb[0];
        const unsigned short* pT = xpn + sb0 + boff;
        uint4 b0 = *(const uint4*)pT;
        uint4 b1 = *(const uint4*)(pT + 32);
        const unsigned short* ap = Afw + t90 * 32768;
#pragma unroll
        for (int mi = 0; mi < 4; ++mi) {
            aC[0][mi] = *(const s16x8*)(ap + mi * 512);
            aC[1][mi] = *(const s16x8*)(ap + 4096 + mi * 512);
        }
        *(uint4*)&Bs[0][0][bx][bcg * 8] = b0;
        *(uint4*)&Bs[0][1][bx][bcg * 8] = b1;
    }
    BARRIER();

#define TC_PH(PP, BUF, AC, AN)                                                   \
    {                                                                            \
        int P_ = (PP);                                                           \
        if (P_ + 1 < NPAIR) {                                                    \
            int slot_ = (P_ + 1) >> 2;                                           \
            int cb0_ = ((P_ + 1) & 3) * 2;                                       \
            int t9_ = st9[slot_], sb_ = sbb[slot_];                              \
            const unsigned short* pT_ = xpn + sb_ + boff + cb0_ * 32;            \
            nb0 = *(const uint4*)pT_;                                            \
            nb1 = *(const uint4*)(pT_ + 32);                                     \
            const unsigned short* ap_ = Afw + (t9_ * 8 + cb0_) * 4096;           \
            _Pragma("unroll")                                                    \
            for (int mi = 0; mi < 4; ++mi) {                                     \
                AN[0][mi] = *(const s16x8*)(ap_ + mi * 512);                     \
                AN[1][mi] = *(const s16x8*)(ap_ + 4096 + mi * 512);              \
            }                                                                    \
        }                                                                        \
        s16x8 bb[2][2];                                                          \
        _Pragma("unroll")                                                        \
        for (int c = 0; c < 2; ++c)                                              \
            _Pragma("unroll")                                                    \
            for (int ni = 0; ni < 2; ++ni)                                       \
                bb[c][ni] = *(const s16x8*)&Bs[BUF][c][wn * 32 + ni * 16 + col][q * 8]; \
        _Pragma("unroll")                                                        \
        for (int c = 0; c < 2; ++c)                                              \
            _Pragma("unroll")                                                    \
            for (int mi = 0; mi < 4; ++mi)                                       \
                _Pragma("unroll")                                                \
                for (int ni = 0; ni < 2; ++ni)                                   \
                    acc[mi][ni] = __builtin_amdgcn_mfma_f32_16x16x32_bf16(AC[c][mi], bb[c][ni], acc[mi][ni], 0, 0, 0); \
        if (P_ + 1 < NPAIR) {                                                    \
            *(uint4*)&Bs[BUF ^ 1][0][bx][bcg * 8] = nb0;                         \
            *(uint4*)&Bs[BUF ^ 1][1][bx][bcg * 8] = nb1;                         \
        }                                                                        \
        BARRIER();                                                               \
    }

    for (int pp = 0; pp < NPAIR; pp += 2) {
        TC_PH(pp,     0, aC, aN);
        TC_PH(pp + 1, 1, aN, aC);
    }
#undef TC_PH

    unsigned short* uppn = upp + (size_t)n * (132 * 132 * 128);
#pragma unroll
    for (int mi = 0; mi < 4; ++mi)
#pragma unroll
        for (int ni = 0; ni < 2; ++ni) {
            int co = wm * 64 + mi * 16 + q * 4;
            int p64 = wn * 32 + ni * 16 + col;
            int xg = 2 * p64 + xpar;
            unsigned short* p = uppn + ((y + 2) * 132 + (xg + 2)) * 128 + co;
            unsigned lo = pk2(acc[mi][ni][0], acc[mi][ni][1]);
            unsigned hi = pk2(acc[mi][ni][2], acc[mi][ni][3]);
            *(uint2*)p = make_uint2(lo, hi);
        }
}

// ============ deform: MFMA GEMM, 2 K-chunks per barrier phase (18 phases) ============
__global__ __launch_bounds__(256) void k_deform3(const unsigned short* __restrict__ upp,
                                                 const unsigned short* __restrict__ A2f,
                                                 const int* __restrict__ ipar,
                                                 const float* __restrict__ fpar,
                                                 float* __restrict__ out) {
    __shared__ unsigned short Bs[2][2][64][40];   // [buf][chunk][px][40]
    __shared__ int sbase[9];
    __shared__ float4 swt[9];
    int t = threadIdx.x;
    int b = blockIdx.x;
    int xcd = b & 7, j = b >> 3;          // j in [0,64)
    int n = xcd >> 2, band = xcd & 3;
    int y = band * 32 + (j & 31);
    int tx0 = (j >> 5) * 64;              // 2 strips of 64
    const unsigned short* uppn = upp + (size_t)n * (132 * 132 * 128);

    int lane = t & 63, w = t >> 6;
    int col = lane & 15, q = lane >> 4;
    int bx = t >> 2, bcg = t & 3;
    int boff = bx * 128 + bcg * 8;

    if (t < 9) {
        int iy = ipar[(n * 9 + t) * 2 + 0], ix = ipar[(n * 9 + t) * 2 + 1];
        float fy = fpar[(n * 9 + t) * 2 + 0], fx = fpar[(n * 9 + t) * 2 + 1];
        sbase[t] = ((y + 2 + iy) * 132 + (tx0 + 2 + ix)) * 128;
        swt[t] = make_float4((1.f - fy) * (1.f - fx), (1.f - fy) * fx, fy * (1.f - fx), fy * fx);
    }

    f32x4 acc[4][4];
#pragma unroll
    for (int mi = 0; mi < 4; ++mi)
#pragma unroll
        for (int ni = 0; ni < 4; ++ni) acc[mi][ni] = (f32x4){0.f, 0.f, 0.f, 0.f};

    __syncthreads();   // sbase/swt visible

    const unsigned short* Afw = A2f + w * 2048 + lane * 8;   // + k*8192 + mi*512
    s16x8 aC[2][4], aN[2][4];
    uint4 cA0, cB0, cC0, cD0, cA1, cB1, cC1, cD1;

    // prologue: pair 0 (chunks 0,1, tap 0)
    {
        const unsigned short* pAt = uppn + sbase[0] + boff;
        const unsigned short* pCt = pAt + 16896;
        float4 cw0 = swt[0];
        uint4 uA0 = *(const uint4*)pAt;
        uint4 uB0 = *(const uint4*)(pAt + 128);
        uint4 uC0 = *(const uint4*)pCt;
        uint4 uD0 = *(const uint4*)(pCt + 128);
        uint4 uA1 = *(const uint4*)(pAt + 32);
        uint4 uB1 = *(const uint4*)(pAt + 160);
        uint4 uC1 = *(const uint4*)(pCt + 32);
        uint4 uD1 = *(const uint4*)(pCt + 160);
#pragma unroll
        for (int mi = 0; mi < 4; ++mi) {
            aC[0][mi] = *(const s16x8*)(Afw + mi * 512);
            aC[1][mi] = *(const s16x8*)(Afw + 8192 + mi * 512);
        }
        blend_store(uA0, uB0, uC0, uD0, cw0, &Bs[0][0][bx][bcg * 8]);
        blend_store(uA1, uB1, uC1, uD1, cw0, &Bs[0][1][bx][bcg * 8]);
    }
    BARRIER();

#define DEF_PH(PP, BUF, AC, AN)                                                  \
    {                                                                            \
        int P_ = (PP);                                                           \
        float4 cwn;                                                              \
        if (P_ + 1 < 18) {                                                       \
            int tap_ = (P_ + 1) >> 1;                                            \
            int sh_ = ((P_ + 1) & 1) * 64;                                       \
            int sb_ = sbase[tap_];                                               \
            cwn = swt[tap_];                                                     \
            const unsigned short* pAt_ = uppn + sb_ + boff + sh_;                \
            const unsigned short* pCt_ = pAt_ + 16896;                           \
            cA0 = *(const uint4*)pAt_;                                           \
            cB0 = *(const uint4*)(pAt_ + 128);                                   \
            cC0 = *(const uint4*)pCt_;                                           \
            cD0 = *(const uint4*)(pCt_ + 128);                                   \
            cA1 = *(const uint4*)(pAt_ + 32);                                    \
            cB1 = *(const uint4*)(pAt_ + 160);                                   \
            cC1 = *(const uint4*)(pCt_ + 32);                                    \
            cD1 = *(const uint4*)(pCt_ + 160);                                   \
            const unsigned short* ap_ = Afw + (P_ + 1) * 16384;                  \
            _Pragma("unroll")                                                    \
            for (int mi = 0; mi < 4; ++mi) {                                     \
                AN[0][mi] = *(const s16x8*)(ap_ + mi * 512);                     \
                AN[1][mi] = *(const s16x8*)(ap_ + 8192 + mi * 512);              \
            }                                                                    \
        }                                                                        \
        s16x8 bb[2][4];                                                          \
        _Pragma("unroll")                                                        \
        for (int c = 0; c < 2; ++c)                                              \
            _Pragma("unroll")                                                    \
            for (int ni = 0; ni < 4; ++ni)                                       \
                bb[c][ni] = *(const s16x8*)&Bs[BUF][c][ni * 16 + col][q * 8];    \
        _Pragma("unroll")                                                        \
        for (int c = 0; c < 2; ++c)                                              \
            _Pragma("unroll")                                                    \
            for (int mi = 0; mi < 4; ++mi)                                       \
                _Pragma("unroll")                                                \
                for (int ni = 0; ni < 4; ++ni)                                   \
                    acc[mi][ni] = __builtin_amdgcn_mfma_f32_16x16x32_bf16(AC[c][mi], bb[c][ni], acc[mi][ni], 0, 0, 0); \
        if (P_ + 1 < 18) {                                                       \
            blend_store(cA0, cB0, cC0, cD0, cwn, &Bs[BUF ^ 1][0][bx][bcg * 8]);  \
            blend_store(cA1, cB1, cC1, cD1, cwn, &Bs[BUF ^ 1][1][bx][bcg * 8]);  \
        }                                                                        \
        BARRIER();                                                               \
    }

    for (int pp = 0; pp < 18; pp += 2) {
        DEF_PH(pp,     0, aC, aN);
        DEF_PH(pp + 1, 1, aN, aC);
    }
#undef DEF_PH

#pragma unroll
    for (int mi = 0; mi < 4; ++mi)
#pragma unroll
        for (int ni = 0; ni < 4; ++ni) {
            int o = w * 64 + mi * 16 + q * 4;
            int xg = tx0 + ni * 16 + col;
            float* p = out + (((size_t)(n * 256 + o)) * 128 + y) * 128 + xg;
            p[0]         = acc[mi][ni][0];
            p[16384]     = acc[mi][ni][1];
            p[2 * 16384] = acc[mi][ni][2];
            p[3 * 16384] = acc[mi][ni][3];
        }
}

extern "C" void kernel_launch(void* const* d_in, const int* in_sizes, int n_in,
                              void* d_out, int out_size, void* d_ws, size_t ws_size,
                              hipStream_t stream) {
    const float* x   = (const float*)d_in[0];
    const float* lat = (const float*)d_in[1];
    const float* tw  = (const float*)d_in[2];
    const float* w1  = (const float*)d_in[3];
    const float* b1  = (const float*)d_in[4];
    const float* w2  = (const float*)d_in[5];
    const float* b2  = (const float*)d_in[6];
    float* out = (float*)d_out;

    char* ws = (char*)d_ws;
    // upp bf16 halo2: 2*132*132*128*2 = 8,921,088 @ 0
    // xp  bf16 pad+1: 2*65*65*256*2   = 4,326,400 @ 8,921,088   (one memset covers both)
    // A2f: 294912*2 = 589,824 @ 13,247,488
    // Awf: 294912*2 = 589,824 @ 13,837,312
    unsigned short* upp = (unsigned short*)ws;
    unsigned short* xp  = (unsigned short*)(ws + 8921088);
    unsigned short* A2f = (unsigned short*)(ws + 13247488);
    unsigned short* Awf = (unsigned short*)(ws + 13837312);
    int*   ipar         = (int*)(ws + 14427136);
    float* fpar         = (float*)(ws + 14427424);

    hipMemsetAsync(ws, 0, 13247488, stream);
    k_prep<<<801, 256, 0, stream>>>(x, lat, tw, w1, b1, w2, b2, xp, A2f, Awf, ipar, fpar);
    k_tconv3<<<512, 256, 0, stream>>>(xp, Awf, upp);
    k_deform3<<<512, 256, 0, stream>>>(upp, A2f, ipar, fpar, out);
}

// Round 4
// 139.056 us; speedup vs baseline: 1.1396x; 1.0254x over previous
//
#include <hip/hip_runtime.h>
#include <hip/hip_fp16.h>
#include <math.h>

typedef __attribute__((ext_vector_type(8))) _Float16 f16x8;
typedef __attribute__((ext_vector_type(4))) float f32x4;

__device__ __forceinline__ unsigned short f2h(float f) {
    __half h = __float2half_rn(f);
    union { __half h; unsigned short u; } v; v.h = h; return v.u;
}
__device__ __forceinline__ unsigned pk2h(float lo, float hi) {
    __half2 h = __floats2half2_rn(lo, hi);
    union { __half2 h; unsigned u; } v; v.h = h; return v.u;
}

// Raw barrier: LDS drained (cross-wave visibility of ds_write), but global
// loads in flight (prefetch) intentionally NOT drained.
#define BARRIER() do { asm volatile("s_waitcnt lgkmcnt(0)" ::: "memory"); \
                       __builtin_amdgcn_s_barrier(); } while (0)

// Packed-f16 bilinear blend: 4 corner uint4s (8 f16 channels each) -> one uint4.
// 16 v_pk_fma_f16 total -- no unpack/repack, no f32 lanes.
__device__ __forceinline__ void blend_store_h(uint4 uA, uint4 uB, uint4 uC, uint4 uD,
                                              __half2 w0, __half2 w1, __half2 w2, __half2 w3,
                                              unsigned short* dst) {
    union U { uint4 u; __half2 h[4]; };
    U a, b, c, d, r;
    a.u = uA; b.u = uB; c.u = uC; d.u = uD;
#pragma unroll
    for (int i = 0; i < 4; ++i)
        r.h[i] = __hfma2(w0, a.h[i], __hfma2(w1, b.h[i], __hfma2(w2, c.h[i], __hmul2(w3, d.h[i]))));
    *(uint4*)dst = r.u;
}

// ============ Fused prep kernel (block-specialized) ============
__global__ __launch_bounds__(256) void k_prep(const float* __restrict__ x,
                                              const float* __restrict__ lat,
                                              const float* __restrict__ tw,
                                              const float* __restrict__ w1,
                                              const float* __restrict__ b1,
                                              const float* __restrict__ w2,
                                              const float* __restrict__ b2,
                                              unsigned short* __restrict__ xp,
                                              unsigned short* __restrict__ A2f,
                                              unsigned short* __restrict__ Awf,
                                              int* __restrict__ ipar,
                                              float* __restrict__ fpar) {
    __shared__ float sm[8420];
    int b = blockIdx.x, t = threadIdx.x;
    if (b == 0) {
        for (int i = t; i < 8192; i += 256) sm[(i >> 7) * 129 + (i & 127)] = w1[i * 9 + 4];
        __syncthreads();
        if (t < 128) {
            int n = t >> 6, o = t & 63;
            float s = b1[o];
            const float* ln = lat + n * 128;
#pragma unroll 8
            for (int c = 0; c < 128; ++c) s += ln[c] * sm[o * 129 + c];
            sm[8256 + t] = fmaxf(s, 0.f);
        }
        __syncthreads();
        if (t < 36) {
            int n = t / 18, j = t % 18;
            float s = b2[j];
            for (int o = 0; o < 64; ++o) s += sm[8256 + n * 64 + o] * w2[(j * 64 + o) * 9 + 4];
            float ov = tanhf(s);
            ov = fminf(fmaxf(ov, -0.999999f), 0.999999f);
            sm[8384 + t] = ov;
        }
        __syncthreads();
        if (t < 36) {
            int n = t / 18, j = t % 18;
            int tap = j >> 1, d = j & 1;
            float ov = sm[8384 + t];
            float fl = floorf(ov);
            int kc = d ? (tap % 3) : (tap / 3);
            ipar[(n * 9 + tap) * 2 + d] = kc - 1 + (int)fl;
            fpar[(n * 9 + tap) * 2 + d] = ov - fl;
        }
    } else if (b < 145) {
        int slot = (b - 1) * 256 + t;
        int l = slot & 63;
        int mi = (slot >> 6) & 3;
        int w = (slot >> 8) & 3;
        int k = slot >> 10;                 // 0..35
        int row = w * 64 + mi * 16 + (l & 15);
        int kq = l >> 4;
        unsigned short v[8];
#pragma unroll
        for (int j = 0; j < 8; ++j) {
            int kcol = k * 32 + kq * 8 + j;  // < 1152
            int tap = kcol >> 7, c = kcol & 127;
            v[j] = f2h(tw[(row * 128 + c) * 9 + tap]);
        }
        unsigned p0 = (unsigned)v[0] | ((unsigned)v[1] << 16);
        unsigned p1 = (unsigned)v[2] | ((unsigned)v[3] << 16);
        unsigned p2 = (unsigned)v[4] | ((unsigned)v[5] << 16);
        unsigned p3 = (unsigned)v[6] | ((unsigned)v[7] << 16);
        *(uint4*)(A2f + slot * 8) = make_uint4(p0, p1, p2, p3);
    } else if (b < 289) {
        int slot = (b - 145) * 256 + t;
        int l = slot & 63;
        int mi = (slot >> 6) & 3;
        int wm = (slot >> 8) & 1;
        int k = slot >> 9;                  // 0..71
        int row = wm * 64 + mi * 16 + (l & 15);
        int kq = l >> 4;
        unsigned short v[8];
#pragma unroll
        for (int j = 0; j < 8; ++j) {
            int kcol = k * 32 + kq * 8 + j;  // < 2304
            int t9 = kcol >> 8, ci = kcol & 255;
            int ky = t9 / 3, kx = t9 - ky * 3;
            v[j] = f2h(tw[(ci * 128 + row) * 9 + (2 - ky) * 3 + (2 - kx)]);
        }
        unsigned p0 = (unsigned)v[0] | ((unsigned)v[1] << 16);
        unsigned p1 = (unsigned)v[2] | ((unsigned)v[3] << 16);
        unsigned p2 = (unsigned)v[4] | ((unsigned)v[5] << 16);
        unsigned p3 = (unsigned)v[6] | ((unsigned)v[7] << 16);
        *(uint4*)(Awf + slot * 8) = make_uint4(p0, p1, p2, p3);
    } else {
        int bb = b - 289;
        int h = bb & 63, cq = (bb >> 6) & 3, n = bb >> 8;
        int c0 = cq * 64;
        {
            int wcol = t & 63, sub = t >> 6;
            for (int r = 0; r < 16; ++r) {
                int ci_l = r * 4 + sub;
                sm[ci_l * 65 + wcol] = x[((n * 256 + c0 + ci_l) * 64 + h) * 64 + wcol];
            }
        }
        __syncthreads();
        int wcol = t >> 2, cg = t & 3;
        unsigned short* dst = xp + (size_t)n * (65 * 65 * 256) + (h * 65 + wcol) * 256 + c0 + cg * 16;
        unsigned pk[8];
#pragma unroll
        for (int j = 0; j < 8; ++j)
            pk[j] = pk2h(sm[(cg * 16 + 2 * j) * 65 + wcol], sm[(cg * 16 + 2 * j + 1) * 65 + wcol]);
        *(uint4*)dst = make_uint4(pk[0], pk[1], pk[2], pk[3]);
        *(uint4*)(dst + 8) = make_uint4(pk[4], pk[5], pk[6], pk[7]);
    }
}

// ============ tconv: parity-decomposed MFMA GEMM, 2 K-chunks per barrier phase ============
__global__ __launch_bounds__(256) void k_tconv3(const unsigned short* __restrict__ xp,
                                                const unsigned short* __restrict__ Awf,
                                                unsigned short* __restrict__ upp) {
    __shared__ unsigned short Bs[2][2][64][40];   // [buf][chunk][px][40]
    __shared__ int st9[4];
    __shared__ int sbb[4];
    int t = threadIdx.x;
    int b = blockIdx.x;
    int phase = b & 1;
    int xpar = ((b >> 1) & 1) ^ phase;
    int n = (b >> 2) & 1;
    int yh = b >> 3;                 // 0..63
    int y = yh * 2 + phase;
    const unsigned short* xpn = xp + (size_t)n * (65 * 65 * 256);

    int lane = t & 63, w = t >> 6;
    int col = lane & 15, q = lane >> 4;
    int wm = w >> 1, wn = w & 1;
    int bx = t >> 2, bcg = t & 3;
    int boff = bx * 256 + bcg * 8;

    int kys[2], kxs[2], nky, nkx;
    if (phase) { kys[0] = 0; kys[1] = 2; nky = 2; } else { kys[0] = 1; kys[1] = 1; nky = 1; }
    if (xpar)  { kxs[0] = 0; kxs[1] = 2; nkx = 2; } else { kxs[0] = 1; kxs[1] = 1; nkx = 1; }
    int nslots = nky * nkx;
    if (t < 4) {
        int tc = t < nslots ? t : 0;
        int a1 = (nkx == 2) ? (tc >> 1) : tc;
        int a2 = (nkx == 2) ? (tc & 1) : 0;
        int ky = kys[a1], kx = kxs[a2];
        st9[t] = ky * 3 + kx;
        int d2 = (y + ky - 1) >> 1;
        int s = (xpar + kx - 1) >> 1;
        sbb[t] = (d2 * 65 + s) * 256;
    }
    int NPAIR = nslots * 4;          // NT/2

    f32x4 acc[4][2];
#pragma unroll
    for (int mi = 0; mi < 4; ++mi)
#pragma unroll
        for (int ni = 0; ni < 2; ++ni) acc[mi][ni] = (f32x4){0.f, 0.f, 0.f, 0.f};

    __syncthreads();   // st9/sbb visible

    const unsigned short* Afw = Awf + wm * 2048 + lane * 8;  // + kA*4096 + mi*512
    f16x8 aC[2][4], aN[2][4];
    uint4 nb0, nb1;

    // prologue: pair 0 (chunks 0,1 of slot 0)
    {
        int t90 = st9[0], sb0 = sbb[0];
        const unsigned short* pT = xpn + sb0 + boff;
        uint4 b0 = *(const uint4*)pT;
        uint4 b1 = *(const uint4*)(pT + 32);
        const unsigned short* ap = Afw + t90 * 32768;
#pragma unroll
        for (int mi = 0; mi < 4; ++mi) {
            aC[0][mi] = *(const f16x8*)(ap + mi * 512);
            aC[1][mi] = *(const f16x8*)(ap + 4096 + mi * 512);
        }
        *(uint4*)&Bs[0][0][bx][bcg * 8] = b0;
        *(uint4*)&Bs[0][1][bx][bcg * 8] = b1;
    }
    BARRIER();

#define TC_PH(PP, BUF, AC, AN)                                                   \
    {                                                                            \
        int P_ = (PP);                                                           \
        if (P_ + 1 < NPAIR) {                                                    \
            int slot_ = (P_ + 1) >> 2;                                           \
            int cb0_ = ((P_ + 1) & 3) * 2;                                       \
            int t9_ = st9[slot_], sb_ = sbb[slot_];                              \
            const unsigned short* pT_ = xpn + sb_ + boff + cb0_ * 32;            \
            nb0 = *(const uint4*)pT_;                                            \
            nb1 = *(const uint4*)(pT_ + 32);                                     \
            const unsigned short* ap_ = Afw + (t9_ * 8 + cb0_) * 4096;           \
            _Pragma("unroll")                                                    \
            for (int mi = 0; mi < 4; ++mi) {                                     \
                AN[0][mi] = *(const f16x8*)(ap_ + mi * 512);                     \
                AN[1][mi] = *(const f16x8*)(ap_ + 4096 + mi * 512);              \
            }                                                                    \
        }                                                                        \
        f16x8 bb[2][2];                                                          \
        _Pragma("unroll")                                                        \
        for (int c = 0; c < 2; ++c)                                              \
            _Pragma("unroll")                                                    \
            for (int ni = 0; ni < 2; ++ni)                                       \
                bb[c][ni] = *(const f16x8*)&Bs[BUF][c][wn * 32 + ni * 16 + col][q * 8]; \
        _Pragma("unroll")                                                        \
        for (int c = 0; c < 2; ++c)                                              \
            _Pragma("unroll")                                                    \
            for (int mi = 0; mi < 4; ++mi)                                       \
                _Pragma("unroll")                                                \
                for (int ni = 0; ni < 2; ++ni)                                   \
                    acc[mi][ni] = __builtin_amdgcn_mfma_f32_16x16x32_f16(AC[c][mi], bb[c][ni], acc[mi][ni], 0, 0, 0); \
        if (P_ + 1 < NPAIR) {                                                    \
            *(uint4*)&Bs[BUF ^ 1][0][bx][bcg * 8] = nb0;                         \
            *(uint4*)&Bs[BUF ^ 1][1][bx][bcg * 8] = nb1;                         \
        }                                                                        \
        BARRIER();                                                               \
    }

    for (int pp = 0; pp < NPAIR; pp += 2) {
        TC_PH(pp,     0, aC, aN);
        TC_PH(pp + 1, 1, aN, aC);
    }
#undef TC_PH

    unsigned short* uppn = upp + (size_t)n * (132 * 132 * 128);
#pragma unroll
    for (int mi = 0; mi < 4; ++mi)
#pragma unroll
        for (int ni = 0; ni < 2; ++ni) {
            int co = wm * 64 + mi * 16 + q * 4;
            int p64 = wn * 32 + ni * 16 + col;
            int xg = 2 * p64 + xpar;
            unsigned short* p = uppn + ((y + 2) * 132 + (xg + 2)) * 128 + co;
            unsigned lo = pk2h(acc[mi][ni][0], acc[mi][ni][1]);
            unsigned hi = pk2h(acc[mi][ni][2], acc[mi][ni][3]);
            *(uint2*)p = make_uint2(lo, hi);
        }
}

// ============ deform: MFMA GEMM, 2 K-chunks per phase, packed-f16 blend ============
__global__ __launch_bounds__(256) void k_deform3(const unsigned short* __restrict__ upp,
                                                 const unsigned short* __restrict__ A2f,
                                                 const int* __restrict__ ipar,
                                                 const float* __restrict__ fpar,
                                                 float* __restrict__ out) {
    __shared__ unsigned short Bs[2][2][64][40];   // [buf][chunk][px][40]
    __shared__ int sbase[9];
    __shared__ __half2 swh[9][4];
    int t = threadIdx.x;
    int b = blockIdx.x;
    int xcd = b & 7, j = b >> 3;          // j in [0,64)
    int n = xcd >> 2, band = xcd & 3;
    int y = band * 32 + (j & 31);
    int tx0 = (j >> 5) * 64;              // 2 strips of 64
    const unsigned short* uppn = upp + (size_t)n * (132 * 132 * 128);

    int lane = t & 63, w = t >> 6;
    int col = lane & 15, q = lane >> 4;
    int bx = t >> 2, bcg = t & 3;
    int boff = bx * 128 + bcg * 8;

    if (t < 9) {
        int iy = ipar[(n * 9 + t) * 2 + 0], ix = ipar[(n * 9 + t) * 2 + 1];
        float fy = fpar[(n * 9 + t) * 2 + 0], fx = fpar[(n * 9 + t) * 2 + 1];
        sbase[t] = ((y + 2 + iy) * 132 + (tx0 + 2 + ix)) * 128;
        swh[t][0] = __float2half2_rn((1.f - fy) * (1.f - fx));
        swh[t][1] = __float2half2_rn((1.f - fy) * fx);
        swh[t][2] = __float2half2_rn(fy * (1.f - fx));
        swh[t][3] = __float2half2_rn(fy * fx);
    }

    f32x4 acc[4][4];
#pragma unroll
    for (int mi = 0; mi < 4; ++mi)
#pragma unroll
        for (int ni = 0; ni < 4; ++ni) acc[mi][ni] = (f32x4){0.f, 0.f, 0.f, 0.f};

    __syncthreads();   // sbase/swh visible

    const unsigned short* Afw = A2f + w * 2048 + lane * 8;   // + k*8192 + mi*512
    f16x8 aC[2][4], aN[2][4];
    uint4 cA0, cB0, cC0, cD0, cA1, cB1, cC1, cD1;

    // prologue: pair 0 (chunks 0,1, tap 0)
    {
        const unsigned short* pAt = uppn + sbase[0] + boff;
        const unsigned short* pCt = pAt + 16896;
        __half2 w0 = swh[0][0], w1 = swh[0][1], w2 = swh[0][2], w3 = swh[0][3];
        uint4 uA0 = *(const uint4*)pAt;
        uint4 uB0 = *(const uint4*)(pAt + 128);
        uint4 uC0 = *(const uint4*)pCt;
        uint4 uD0 = *(const uint4*)(pCt + 128);
        uint4 uA1 = *(const uint4*)(pAt + 32);
        uint4 uB1 = *(const uint4*)(pAt + 160);
        uint4 uC1 = *(const uint4*)(pCt + 32);
        uint4 uD1 = *(const uint4*)(pCt + 160);
#pragma unroll
        for (int mi = 0; mi < 4; ++mi) {
            aC[0][mi] = *(const f16x8*)(Afw + mi * 512);
            aC[1][mi] = *(const f16x8*)(Afw + 8192 + mi * 512);
        }
        blend_store_h(uA0, uB0, uC0, uD0, w0, w1, w2, w3, &Bs[0][0][bx][bcg * 8]);
        blend_store_h(uA1, uB1, uC1, uD1, w0, w1, w2, w3, &Bs[0][1][bx][bcg * 8]);
    }
    BARRIER();

#define DEF_PH(PP, BUF, AC, AN)                                                  \
    {                                                                            \
        int P_ = (PP);                                                           \
        __half2 w0_, w1_, w2_, w3_;                                              \
        if (P_ + 1 < 18) {                                                       \
            int tap_ = (P_ + 1) >> 1;                                            \
            int sh_ = ((P_ + 1) & 1) * 64;                                       \
            int sb_ = sbase[tap_];                                               \
            w0_ = swh[tap_][0]; w1_ = swh[tap_][1];                              \
            w2_ = swh[tap_][2]; w3_ = swh[tap_][3];                              \
            const unsigned short* pAt_ = uppn + sb_ + boff + sh_;                \
            const unsigned short* pCt_ = pAt_ + 16896;                           \
            cA0 = *(const uint4*)pAt_;                                           \
            cB0 = *(const uint4*)(pAt_ + 128);                                   \
            cC0 = *(const uint4*)pCt_;                                           \
            cD0 = *(const uint4*)(pCt_ + 128);                                   \
            cA1 = *(const uint4*)(pAt_ + 32);                                    \
            cB1 = *(const uint4*)(pAt_ + 160);                                   \
            cC1 = *(const uint4*)(pCt_ + 32);                                    \
            cD1 = *(const uint4*)(pCt_ + 160);                                   \
            const unsigned short* ap_ = Afw + (P_ + 1) * 16384;                  \
            _Pragma("unroll")                                                    \
            for (int mi = 0; mi < 4; ++mi) {                                     \
                AN[0][mi] = *(const f16x8*)(ap_ + mi * 512);                     \
                AN[1][mi] = *(const f16x8*)(ap_ + 8192 + mi * 512);              \
            }                                                                    \
        }                                                                        \
        f16x8 bb[2][4];                                                          \
        _Pragma("unroll")                                                        \
        for (int c = 0; c < 2; ++c)                                              \
            _Pragma("unroll")                                                    \
            for (int ni = 0; ni < 4; ++ni)                                       \
                bb[c][ni] = *(const f16x8*)&Bs[BUF][c][ni * 16 + col][q * 8];    \
        _Pragma("unroll")                                                        \
        for (int c = 0; c < 2; ++c)                                              \
            _Pragma("unroll")                                                    \
            for (int mi = 0; mi < 4; ++mi)                                       \
                _Pragma("unroll")                                                \
                for (int ni = 0; ni < 4; ++ni)                                   \
                    acc[mi][ni] = __builtin_amdgcn_mfma_f32_16x16x32_f16(AC[c][mi], bb[c][ni], acc[mi][ni], 0, 0, 0); \
        if (P_ + 1 < 18) {                                                       \
            blend_store_h(cA0, cB0, cC0, cD0, w0_, w1_, w2_, w3_, &Bs[BUF ^ 1][0][bx][bcg * 8]); \
            blend_store_h(cA1, cB1, cC1, cD1, w0_, w1_, w2_, w3_, &Bs[BUF ^ 1][1][bx][bcg * 8]); \
        }                                                                        \
        BARRIER();                                                               \
    }

    for (int pp = 0; pp < 18; pp += 2) {
        DEF_PH(pp,     0, aC, aN);
        DEF_PH(pp + 1, 1, aN, aC);
    }
#undef DEF_PH

#pragma unroll
    for (int mi = 0; mi < 4; ++mi)
#pragma unroll
        for (int ni = 0; ni < 4; ++ni) {
            int o = w * 64 + mi * 16 + q * 4;
            int xg = tx0 + ni * 16 + col;
            float* p = out + (((size_t)(n * 256 + o)) * 128 + y) * 128 + xg;
            p[0]         = acc[mi][ni][0];
            p[16384]     = acc[mi][ni][1];
            p[2 * 16384] = acc[mi][ni][2];
            p[3 * 16384] = acc[mi][ni][3];
        }
}

extern "C" void kernel_launch(void* const* d_in, const int* in_sizes, int n_in,
                              void* d_out, int out_size, void* d_ws, size_t ws_size,
                              hipStream_t stream) {
    const float* x   = (const float*)d_in[0];
    const float* lat = (const float*)d_in[1];
    const float* tw  = (const float*)d_in[2];
    const float* w1  = (const float*)d_in[3];
    const float* b1  = (const float*)d_in[4];
    const float* w2  = (const float*)d_in[5];
    const float* b2  = (const float*)d_in[6];
    float* out = (float*)d_out;

    char* ws = (char*)d_ws;
    // upp f16 halo2: 2*132*132*128*2 = 8,921,088 @ 0
    // xp  f16 pad+1: 2*65*65*256*2   = 4,326,400 @ 8,921,088   (one memset covers both)
    // A2f: 294912*2 = 589,824 @ 13,247,488
    // Awf: 294912*2 = 589,824 @ 13,837,312
    unsigned short* upp = (unsigned short*)ws;
    unsigned short* xp  = (unsigned short*)(ws + 8921088);
    unsigned short* A2f = (unsigned short*)(ws + 13247488);
    unsigned short* Awf = (unsigned short*)(ws + 13837312);
    int*   ipar         = (int*)(ws + 14427136);
    float* fpar         = (float*)(ws + 14427424);

    hipMemsetAsync(ws, 0, 13247488, stream);
    k_prep<<<801, 256, 0, stream>>>(x, lat, tw, w1, b1, w2, b2, xp, A2f, Awf, ipar, fpar);
    k_tconv3<<<512, 256, 0, stream>>>(xp, Awf, upp);
    k_deform3<<<512, 256, 0, stream>>>(upp, A2f, ipar, fpar, out);
}